// Round 1
// baseline (328.336 us; speedup 1.0000x reference)
//
#include <hip/hip_runtime.h>
#include <hip/hip_bf16.h>

// ActorNetwork fused pipeline for MI355X.
// Key restructuring: GAT collapsed via wa = W_gat @ a (per head) and
// Wbig = [fusion_W[0:129]; W_gat x fusion_W[129:]] so neighbor_obs is read once.
// Downstream GEMMs use bf16 MFMA with hi/lo split (3 passes) for fp32-like accuracy.

typedef unsigned short u16;
typedef unsigned int   u32;
typedef __attribute__((ext_vector_type(8))) short bf16x8;
typedef __attribute__((ext_vector_type(4))) float f32x4;

#define NB_B   8192
#define NB_N   64
#define D_NB   128
#define KFUSE  672   // 641 padded to 21*32
#define ACT_TOT (8192*16)

__device__ __forceinline__ u16 f2bf(float x){
  u32 u = __float_as_uint(x);
  u += 0x7fffu + ((u >> 16) & 1u);   // round-to-nearest-even
  return (u16)(u >> 16);
}
__device__ __forceinline__ float bf2f(u16 h){ return __uint_as_float(((u32)h) << 16); }

// ---------- tiny preprocessing kernels ----------

// mask dtype probe: bool bytes vs int32 (also covers f32 via nonzero-int read)
__global__ void k_probe(const unsigned char* __restrict__ m, int* flag){
  if(threadIdx.x == 0){
    int s = 0;
    for(int i = 1; i < 256; i += 4) s += m[i];
    *flag = (s == 0) ? 1 : 0;   // 1 => 4-byte elements
  }
}

// wa_src[k][h], wa_dst[k][h]
__global__ void k_wa(const float* __restrict__ Wg, const float* __restrict__ ag,
                     float* __restrict__ was, float* __restrict__ wad){
  int t = threadIdx.x;            // 512
  int k = t & 127, h = t >> 7;
  float s = 0.f, d = 0.f;
  for(int f = 0; f < 64; ++f){
    float w = Wg[k*256 + h*64 + f];
    s += w * ag[h*128 + f];
    d += w * ag[h*128 + 64 + f];
  }
  was[k*4 + h] = s; wad[k*4 + h] = d;
}

// Wbig (672 x 256) fp32: rows 0..128 = fusion_W rows; 129+h*128+k = W_gat x fusion_W; pad rows 0.
__global__ void k_wbig(const float* __restrict__ fW, const float* __restrict__ Wg,
                       float* __restrict__ wbig){
  int r = blockIdx.x, j = threadIdx.x;  // 672 x 256
  float v;
  if(r < 129) v = fW[r*256 + j];
  else if(r < 641){
    int h = (r - 129) >> 7, kk = (r - 129) & 127;
    float s = 0.f;
    for(int f = 0; f < 64; ++f) s += Wg[kk*256 + h*64 + f] * fW[(129 + h*64 + f)*256 + j];
    v = s;
  } else v = 0.f;
  wbig[r*256 + j] = v;
}

// fp32 weight (K x N, K = 32*KT exactly) -> MFMA B-fragment order, hi/lo bf16.
// frag(kt,nt): lane l, elem i <-> W[kt*32 + (l>>4)*8 + i][nt*16 + (l&15)]
__global__ void k_frag(const float* __restrict__ src, int N, int NT,
                       u16* __restrict__ dhi, u16* __restrict__ dlo){
  int frag = blockIdx.x, l = threadIdx.x;   // 64 threads
  int kt = frag / NT, nt = frag % NT;
  int kbase = kt*32 + (l >> 4)*8, n = nt*16 + (l & 15);
  size_t o = ((size_t)frag*64 + l)*8;
  for(int i = 0; i < 8; ++i){
    float w = src[(size_t)(kbase + i)*N + n];
    u16 h = f2bf(w);
    dhi[o + i] = h;
    dlo[o + i] = f2bf(w - bf2f(h));
  }
}

// fp32 -> (hi,lo) bf16, 8 elems/thread
__global__ void k_split(const float* __restrict__ x, u16* __restrict__ hi,
                        u16* __restrict__ lo, int n8){
  int i = blockIdx.x*blockDim.x + threadIdx.x;
  if(i >= n8) return;
  const float4* p = (const float4*)x + (size_t)i*2;
  float4 v0 = p[0], v1 = p[1];
  float vv[8] = {v0.x,v0.y,v0.z,v0.w,v1.x,v1.y,v1.z,v1.w};
  u16 h8[8], l8[8];
  #pragma unroll
  for(int q = 0; q < 8; ++q){ u16 h = f2bf(vv[q]); h8[q] = h; l8[q] = f2bf(vv[q] - bf2f(h)); }
  uint4 uh = { (u32)h8[0] | ((u32)h8[1]<<16), (u32)h8[2] | ((u32)h8[3]<<16),
               (u32)h8[4] | ((u32)h8[5]<<16), (u32)h8[6] | ((u32)h8[7]<<16) };
  uint4 ul = { (u32)l8[0] | ((u32)l8[1]<<16), (u32)l8[2] | ((u32)l8[3]<<16),
               (u32)l8[4] | ((u32)l8[5]<<16), (u32)l8[6] | ((u32)l8[7]<<16) };
  *(uint4*)(hi + (size_t)i*8) = uh;
  *(uint4*)(lo + (size_t)i*8) = ul;
}

// ---------- GAT kernel: one block per batch row ----------
__global__ __launch_bounds__(256) void k_gat(
    const float* __restrict__ nbg, const float* __restrict__ node,
    const void* __restrict__ maskp, const int* __restrict__ flagp,
    const float* __restrict__ was, const float* __restrict__ wad,
    u16* __restrict__ xhi, u16* __restrict__ xlo)
{
  __shared__ float s_nb[8192];      // 64x128, float4-swizzled
  __shared__ float s_was[512], s_wad[512];
  __shared__ float s_ep[4*64*4];    // [c][n][h]
  __shared__ float s_esp[16];       // [c][h]
  __shared__ float s_alpha[256];    // [h][n]
  int b = blockIdx.x, t = threadIdx.x;
  const float* nb = nbg + (size_t)b*8192;
  const int isint = *flagp;

  s_was[t] = was[t]; s_was[t+256] = was[t+256];
  s_wad[t] = wad[t]; s_wad[t+256] = wad[t+256];

  // enc part of x_cat: [sin, cos, node_obs[1:128]] + zero pad 641..671
  if(t < 129){
    float v;
    if(t < 2){
      float ph = node[(size_t)b*128] * (6.2831853071795864769f / 24.0f);
      v = (t == 0) ? sinf(ph) : cosf(ph);
    } else v = node[(size_t)b*128 + (t-1)];
    u16 h = f2bf(v);
    size_t o = (size_t)b*KFUSE + t;
    xhi[o] = h; xlo[o] = f2bf(v - bf2f(h));
  } else if(t < 160){
    size_t o = (size_t)b*KFUSE + 641 + (t - 129);
    xhi[o] = 0; xlo[o] = 0;
  }
  __syncthreads();

  // stage 1: e_dst partials over k-quarters, stash nb in LDS (swizzled)
  int n = t & 63, c = t >> 6;
  float ad0=0.f, ad1=0.f, ad2=0.f, ad3=0.f;
  float as0=0.f, as1=0.f, as2=0.f, as3=0.f;
  bool row0 = (n == 0);
  #pragma unroll
  for(int q = 0; q < 8; ++q){
    float4 v = *(const float4*)(nb + n*128 + c*32 + q*4);
    int xcol = (c*8 + q) ^ (n & 31);
    *(float4*)(s_nb + (n*32 + xcol)*4) = v;
    float vv[4] = {v.x, v.y, v.z, v.w};
    #pragma unroll
    for(int i2 = 0; i2 < 4; ++i2){
      int k = c*32 + q*4 + i2;
      float4 wd = *(const float4*)(s_wad + k*4);
      float x = vv[i2];
      ad0 += x*wd.x; ad1 += x*wd.y; ad2 += x*wd.z; ad3 += x*wd.w;
      if(row0){
        float4 wsv = *(const float4*)(s_was + k*4);
        as0 += x*wsv.x; as1 += x*wsv.y; as2 += x*wsv.z; as3 += x*wsv.w;
      }
    }
  }
  s_ep[(c*64+n)*4+0]=ad0; s_ep[(c*64+n)*4+1]=ad1; s_ep[(c*64+n)*4+2]=ad2; s_ep[(c*64+n)*4+3]=ad3;
  if(row0){ s_esp[c*4+0]=as0; s_esp[c*4+1]=as1; s_esp[c*4+2]=as2; s_esp[c*4+3]=as3; }
  __syncthreads();

  // stage 2 + softmax: thread t -> (h = t>>6 == wave id, n = lane)
  {
    int n2 = t & 63, h2 = t >> 6;
    float ed = s_ep[(0*64+n2)*4+h2] + s_ep[(1*64+n2)*4+h2]
             + s_ep[(2*64+n2)*4+h2] + s_ep[(3*64+n2)*4+h2];
    float es = s_esp[0*4+h2] + s_esp[4+h2] + s_esp[8+h2] + s_esp[12+h2];
    float e = es + ed;
    e = (e > 0.f) ? e : 0.2f*e;
    bool valid;
    if(isint) valid = ((const u32*)maskp)[(size_t)b*64 + n2] != 0u;
    else      valid = ((const unsigned char*)maskp)[(size_t)b*64 + n2] != 0;
    float ev = valid ? e : -1e30f;
    float m = ev;
    for(int off = 32; off; off >>= 1) m = fmaxf(m, __shfl_xor(m, off));
    float p = (ev > -1e29f) ? expf(ev - m) : 0.f;
    float s = p;
    for(int off = 32; off; off >>= 1) s += __shfl_xor(s, off);
    s_alpha[t] = p / s;   // layout [h][n] since t = h*64+n
  }
  __syncthreads();

  // stage 3: wnb[h][k] = sum_n alpha[n,h]*nb[n,k]; write x_cat cols 129+h*128+k
  {
    int k = t & 127, hp = t >> 7;
    int x4 = k >> 2, sub = k & 3;
    float a0 = 0.f, a1 = 0.f;
    for(int nn = 0; nn < 64; ++nn){
      float v = s_nb[(nn*32 + (x4 ^ (nn & 31)))*4 + sub];
      a0 += v * s_alpha[(hp*2+0)*64 + nn];
      a1 += v * s_alpha[(hp*2+1)*64 + nn];
    }
    #pragma unroll
    for(int ii = 0; ii < 2; ++ii){
      int h = hp*2 + ii;
      float val = ii ? a1 : a0;
      u16 hh = f2bf(val);
      size_t o = (size_t)b*KFUSE + 129 + h*128 + k;
      xhi[o] = hh; xlo[o] = f2bf(val - bf2f(hh));
    }
  }
}

// ---------- split-bf16 MFMA GEMM ----------
// Y(M x NTT*16) = X(M x KT*32) @ W + bias.  X row-major hi/lo bf16; W in fragment order.
// EPI: 0 = relu -> hi/lo bf16; 1 = f32; 2 = relu -> f32;
//      3 = col<512: outf += y (accumulate into gi), col>=512: outf2[row*256+col-512] = y
template<int KT, int NTT, int EPI>
__global__ __launch_bounds__(256) void k_gemm(
    const u16* __restrict__ xhi, const u16* __restrict__ xlo,
    const u16* __restrict__ wfhi, const u16* __restrict__ wflo,
    const float* __restrict__ bias,
    float* __restrict__ outf, float* __restrict__ outf2,
    u16* __restrict__ ohi, u16* __restrict__ olo)
{
  const int KP = KT*32, NTOT = NTT*16;
  int l = threadIdx.x & 63, wv = threadIdx.x >> 6;
  int m0 = blockIdx.x*64 + wv*16;
  int nt0 = blockIdx.y*4;
  f32x4 acc[4] = {{0.f,0.f,0.f,0.f},{0.f,0.f,0.f,0.f},{0.f,0.f,0.f,0.f},{0.f,0.f,0.f,0.f}};
  const size_t arow = (size_t)(m0 + (l & 15))*KP + (size_t)((l >> 4)*8);
  for(int kt = 0; kt < KT; ++kt){
    bf16x8 ah = *(const bf16x8*)(xhi + arow + kt*32);
    bf16x8 al = *(const bf16x8*)(xlo + arow + kt*32);
    #pragma unroll
    for(int fc = 0; fc < 4; ++fc){
      size_t bo = ((size_t)(kt*NTT + nt0 + fc)*64 + l)*8;
      bf16x8 bh = *(const bf16x8*)(wfhi + bo);
      bf16x8 bl = *(const bf16x8*)(wflo + bo);
      acc[fc] = __builtin_amdgcn_mfma_f32_16x16x32_bf16(ah, bh, acc[fc], 0, 0, 0);
      acc[fc] = __builtin_amdgcn_mfma_f32_16x16x32_bf16(ah, bl, acc[fc], 0, 0, 0);
      acc[fc] = __builtin_amdgcn_mfma_f32_16x16x32_bf16(al, bh, acc[fc], 0, 0, 0);
    }
  }
  int r0 = m0 + (l >> 4)*4;
  #pragma unroll
  for(int fc = 0; fc < 4; ++fc){
    int col = (nt0 + fc)*16 + (l & 15);
    float bv = bias[col];
    #pragma unroll
    for(int j = 0; j < 4; ++j){
      float y = acc[fc][j] + bv;
      int row = r0 + j;
      if(EPI == 0){
        y = fmaxf(y, 0.f);
        u16 h = f2bf(y);
        size_t o = (size_t)row*NTOT + col;
        ohi[o] = h; olo[o] = f2bf(y - bf2f(h));
      } else if(EPI == 1){
        outf[(size_t)row*NTOT + col] = y;
      } else if(EPI == 2){
        outf[(size_t)row*NTOT + col] = fmaxf(y, 0.f);
      } else {
        if(col < 512) outf[(size_t)row*768 + col] += y;
        else          outf2[(size_t)row*256 + (col - 512)] = y;
      }
    }
  }
}

// ---------- GRU gates + LayerNorm (one block per row) ----------
__global__ __launch_bounds__(256) void k_gru_ln(
    const float* __restrict__ gi, const float* __restrict__ hnb,
    const float* __restrict__ hin, const float* __restrict__ lng,
    const float* __restrict__ lnb, float* __restrict__ hout,
    u16* __restrict__ belhi, u16* __restrict__ bello)
{
  __shared__ float red[8];
  int b = blockIdx.x, j = threadIdx.x;
  size_t o = (size_t)b*768;
  float rsum = gi[o + j];          // ir+hr (+both biases)
  float zsum = gi[o + 256 + j];    // iz+hz
  float in_  = gi[o + 512 + j];    // in + bih
  float hn   = hnb[(size_t)b*256 + j];  // hn + bhh
  float h    = hin[(size_t)b*256 + j];
  float r = 1.f/(1.f + expf(-rsum));
  float z = 1.f/(1.f + expf(-zsum));
  float nn = tanhf(in_ + r*hn);
  float hnew = (1.f - z)*nn + z*h;
  hout[(size_t)b*256 + j] = hnew;
  float s1 = hnew, s2 = hnew*hnew;
  for(int off = 32; off; off >>= 1){ s1 += __shfl_xor(s1, off); s2 += __shfl_xor(s2, off); }
  int wv = j >> 6;
  if((j & 63) == 0){ red[wv] = s1; red[4 + wv] = s2; }
  __syncthreads();
  float t1 = red[0]+red[1]+red[2]+red[3];
  float t2 = red[4]+red[5]+red[6]+red[7];
  float mu  = t1 * (1.f/256.f);
  float var = t2 * (1.f/256.f) - mu*mu;
  float bel = (hnew - mu)*rsqrtf(var + 1e-5f)*lng[j] + lnb[j];
  u16 hb = f2bf(bel);
  size_t ob = (size_t)b*256 + j;
  belhi[ob] = hb; bello[ob] = f2bf(bel - bf2f(hb));
}

// ---------- W3 head + project_power (16 rows/block, 16 lanes/row) ----------
__global__ __launch_bounds__(256) void k_head(
    const float* __restrict__ x2, const float* __restrict__ W3,
    const float* __restrict__ b3, float* __restrict__ act)
{
  __shared__ float sW[2048];
  int t = threadIdx.x;
  for(int i = t; i < 2048; i += 256) sW[i] = W3[i];
  __syncthreads();
  int rl = t >> 4, j = t & 15;
  int b = blockIdx.x*16 + rl;
  const float* xr = x2 + (size_t)b*128;
  float raw = b3[j];
  #pragma unroll 8
  for(int k4 = 0; k4 < 32; ++k4){
    float4 v = *(const float4*)(xr + k4*4);
    raw += v.x*sW[(k4*4+0)*16 + j] + v.y*sW[(k4*4+1)*16 + j]
         + v.z*sW[(k4*4+2)*16 + j] + v.w*sW[(k4*4+3)*16 + j];
  }
  float c0 = fminf(fmaxf(raw, 0.f), 0.5f);
  float tot = c0;
  for(int off = 8; off; off >>= 1) tot += __shfl_xor(tot, off);
  float mx = raw;
  for(int off = 8; off; off >>= 1) mx = fmaxf(mx, __shfl_xor(mx, off));
  bool feas = (tot <= 1.0f);
  float lo = 0.f, hi = fmaxf(mx, 0.f);
  for(int it = 0; it < 60; ++it){
    float mid = 0.5f*(lo + hi);
    float s = fminf(fmaxf(raw - mid, 0.f), 0.5f);
    for(int off = 8; off; off >>= 1) s += __shfl_xor(s, off);
    bool over = s > 1.0f;
    lo = over ? mid : lo;
    hi = over ? hi : mid;
  }
  float muv = feas ? 0.f : hi;
  act[(size_t)b*16 + j] = fminf(fmaxf(raw - muv, 0.f), 0.5f);
}

// ---------- workspace layout (bytes) ----------
#define OFF_FLAG   0u
#define OFF_WAS    256u
#define OFF_WAD    2304u
#define OFF_WBIG   4352u
#define OFF_FFH    692480u
#define OFF_FFL    1036544u
#define OFF_FIH    1380608u
#define OFF_FIL    1773824u
#define OFF_FHH    2167040u
#define OFF_FHL    2560256u
#define OFF_F1H    2953472u
#define OFF_F1L    3084544u
#define OFF_F2H    3215616u
#define OFF_F2L    3281152u
#define OFF_XCATH  3346688u
#define OFF_XCATL  14356736u
// aliases into dead x_cat region:
#define OFF_BELH   3346688u
#define OFF_BELL   7540992u
#define OFF_X1H    11735296u
#define OFF_X1L    15929600u
#define OFF_X2     20123904u
#define OFF_FSH    25366784u
#define OFF_FSL    29561088u
#define OFF_HHI    33755392u
#define OFF_HLO    37949696u
#define OFF_GI     42144000u
#define OFF_HNB    67309824u
// total needed: 75,698,432 bytes

extern "C" void kernel_launch(void* const* d_in, const int* in_sizes, int n_in,
                              void* d_out, int out_size, void* d_ws, size_t ws_size,
                              hipStream_t stream){
  const float* node   = (const float*)d_in[0];
  const float* nbr    = (const float*)d_in[1];
  const void*  mask   = d_in[2];
  const float* hidden = (const float*)d_in[3];
  const float* Wg     = (const float*)d_in[4];
  const float* ag     = (const float*)d_in[5];
  const float* fW     = (const float*)d_in[6];
  const float* fb     = (const float*)d_in[7];
  const float* Wih    = (const float*)d_in[8];
  const float* bih    = (const float*)d_in[9];
  const float* Whh    = (const float*)d_in[10];
  const float* bhh    = (const float*)d_in[11];
  const float* lng    = (const float*)d_in[12];
  const float* lnb    = (const float*)d_in[13];
  const float* W1     = (const float*)d_in[14];
  const float* b1     = (const float*)d_in[15];
  const float* W2     = (const float*)d_in[16];
  const float* b2     = (const float*)d_in[17];
  const float* W3     = (const float*)d_in[18];
  const float* b3     = (const float*)d_in[19];
  char* ws = (char*)d_ws;
  float* out = (float*)d_out;

  int*   flag = (int*)  (ws + OFF_FLAG);
  float* was  = (float*)(ws + OFF_WAS);
  float* wad  = (float*)(ws + OFF_WAD);
  float* wbig = (float*)(ws + OFF_WBIG);
  u16* ffh = (u16*)(ws + OFF_FFH);  u16* ffl = (u16*)(ws + OFF_FFL);
  u16* fih = (u16*)(ws + OFF_FIH);  u16* fil = (u16*)(ws + OFF_FIL);
  u16* fhh = (u16*)(ws + OFF_FHH);  u16* fhl = (u16*)(ws + OFF_FHL);
  u16* f1h = (u16*)(ws + OFF_F1H);  u16* f1l = (u16*)(ws + OFF_F1L);
  u16* f2h = (u16*)(ws + OFF_F2H);  u16* f2l = (u16*)(ws + OFF_F2L);
  u16* xh  = (u16*)(ws + OFF_XCATH); u16* xl = (u16*)(ws + OFF_XCATL);
  u16* beh = (u16*)(ws + OFF_BELH); u16* bel = (u16*)(ws + OFF_BELL);
  u16* x1h = (u16*)(ws + OFF_X1H);  u16* x1l = (u16*)(ws + OFF_X1L);
  float* x2 = (float*)(ws + OFF_X2);
  u16* fsh = (u16*)(ws + OFF_FSH);  u16* fsl = (u16*)(ws + OFF_FSL);
  u16* hhi = (u16*)(ws + OFF_HHI);  u16* hlo = (u16*)(ws + OFF_HLO);
  float* gi  = (float*)(ws + OFF_GI);
  float* hnb = (float*)(ws + OFF_HNB);

  // preprocessing (constant folding of weights)
  k_probe<<<1, 64, 0, stream>>>((const unsigned char*)mask, flag);
  k_wa<<<1, 512, 0, stream>>>(Wg, ag, was, wad);
  k_wbig<<<672, 256, 0, stream>>>(fW, Wg, wbig);
  k_frag<<<21*16, 64, 0, stream>>>(wbig, 256, 16, ffh, ffl);
  k_frag<<<8*48, 64, 0, stream>>>(Wih, 768, 48, fih, fil);
  k_frag<<<8*48, 64, 0, stream>>>(Whh, 768, 48, fhh, fhl);
  k_frag<<<8*16, 64, 0, stream>>>(W1, 256, 16, f1h, f1l);
  k_frag<<<8*8,  64, 0, stream>>>(W2, 128, 8, f2h, f2l);
  k_split<<<1024, 256, 0, stream>>>(hidden, hhi, hlo, 262144);

  // GAT -> x_cat
  k_gat<<<8192, 256, 0, stream>>>(nbr, node, mask, flag, was, wad, xh, xl);

  // fused = relu(x_cat @ Wbig + fb)
  k_gemm<21,16,0><<<dim3(128,4), 256, 0, stream>>>(xh, xl, ffh, ffl, fb, nullptr, nullptr, fsh, fsl);
  // gi = fused @ Wih + bih
  k_gemm<8,48,1><<<dim3(128,12), 256, 0, stream>>>(fsh, fsl, fih, fil, bih, gi, nullptr, nullptr, nullptr);
  // gh = h @ Whh + bhh; rz-parts accumulate into gi, n-part -> hnb
  k_gemm<8,48,3><<<dim3(128,12), 256, 0, stream>>>(hhi, hlo, fhh, fhl, bhh, gi, hnb, nullptr, nullptr);
  // gates + LN
  k_gru_ln<<<8192, 256, 0, stream>>>(gi, hnb, hidden, lng, lnb, out + ACT_TOT, beh, bel);
  // MLP
  k_gemm<8,16,0><<<dim3(128,4), 256, 0, stream>>>(beh, bel, f1h, f1l, b1, nullptr, nullptr, x1h, x1l);
  k_gemm<8,8,2><<<dim3(128,2), 256, 0, stream>>>(x1h, x1l, f2h, f2l, b2, x2, nullptr, nullptr, nullptr);
  // head + projection
  k_head<<<512, 256, 0, stream>>>(x2, W3, b3, out);
}